// Round 9
// baseline (173.860 us; speedup 1.0000x reference)
//
#include <hip/hip_runtime.h>

// Problem: B=8, S=2048, H=1024, D=64. fp32 in, fp32 out.
// out = softmax_causal(q k^T) / sqrt(H) @ v   (softmax FIRST, then /32)

typedef float     f32x4 __attribute__((ext_vector_type(4)));
typedef _Float16  f16x8 __attribute__((ext_vector_type(8)));
typedef _Float16  f16x4 __attribute__((ext_vector_type(4)));

// ---------------------------------------------------------------------------
// Kernel 1: pack W{q,k,v} into MFMA B-fragment order (f16) via LDS transpose.
__global__ __launch_bounds__(256) void wt_prep(const float* __restrict__ Wq,
                                               const float* __restrict__ Wk,
                                               const float* __restrict__ Wv,
                                               _Float16* __restrict__ WtF) {
  const int w  = blockIdx.x >> 4;              // which W
  const int kt = blockIdx.x & 15;              // k-tile of 64
  const float* src = (w == 0) ? Wq : (w == 1 ? Wk : Wv);
  __shared__ _Float16 ls[64][72];              // [local k][n], padded
  const int t = threadIdx.x;
  {
    int rr = t >> 4;                           // 0..15
    int c4 = (t & 15) * 4;
    #pragma unroll
    for (int ri = 0; ri < 4; ++ri) {
      int k = rr + ri * 16;                    // local k 0..63
      f32x4 f = *(const f32x4*)&src[(size_t)(kt * 64 + k) * 64 + c4];
      #pragma unroll
      for (int j = 0; j < 4; ++j) ls[k][c4 + j] = (_Float16)f[j];
    }
  }
  __syncthreads();
  const int lane = t & 63, l16 = lane & 15, quad = lane >> 4;
  #pragma unroll
  for (int h = 0; h < 2; ++h) {
    int fid     = h * 4 + (t >> 6);            // 0..7
    int kstep_l = fid >> 2;                    // 0..1
    int ntl     = fid & 3;                     // 0..3
    int nt      = w * 4 + ntl;
    int kstep   = kt * 2 + kstep_l;
    f16x8 o;
    #pragma unroll
    for (int j = 0; j < 8; ++j) o[j] = ls[kstep_l * 32 + quad * 8 + j][ntl * 16 + l16];
    *(f16x8*)&WtF[((size_t)(kstep * 12 + nt) * 64 + lane) * 8] = o;
  }
}

// ---------------------------------------------------------------------------
// Kernel 2: QKV projection. XCD-aligned block remap kept (batch = bid&7) --
// affinity partner of attn_part's b = blockIdx&7.
__global__ __launch_bounds__(512, 4) void qkv_gemm(const float* __restrict__ x,
                                                   const _Float16* __restrict__ WtF,
                                                   const float* __restrict__ bq,
                                                   const float* __restrict__ bk,
                                                   const float* __restrict__ bv,
                                                   _Float16* __restrict__ qo,
                                                   _Float16* __restrict__ ko,
                                                   _Float16* __restrict__ vt) {
  __shared__ _Float16 xs[32 * 1024];           // exactly 64 KB
  const int tid  = threadIdx.x;
  const int wave = tid >> 6, lane = tid & 63;
  const int l16  = lane & 15, quad = lane >> 4;
  const int mhalf = wave >> 2;                 // 0..1
  const int ngrp  = wave & 3;                  // 0..3
  const int bid   = blockIdx.x;
  const int m0    = (((bid & 7) << 6) + (bid >> 3)) * 32;  // batch=bid&7, tile=bid>>3

  // --- stage x tile (fp32 -> f16), coalesced: 16-lane groups read 256B runs
  {
    int row   = tid >> 4;                      // 0..31
    int cbase = (tid & 15) * 4;
    const float* xrow = x + (size_t)(m0 + row) * 1024;
    int key = row & 7;
    #pragma unroll
    for (int j = 0; j < 16; ++j) {
      int col = cbase + j * 64;
      f32x4 f = *(const f32x4*)&xrow[col];
      f16x4 hh;
      #pragma unroll
      for (int e = 0; e < 4; ++e) hh[e] = (_Float16)f[e];
      int g   = col >> 3;                      // granule index 0..127
      int sub = col & 7;                       // 0 or 4
      *(f16x4*)&xs[(size_t)row * 1024 + (size_t)((g ^ key) << 3) + sub] = hh;
    }
  }
  __syncthreads();

  f32x4 acc0 = (f32x4){0.f,0.f,0.f,0.f};
  f32x4 acc1 = (f32x4){0.f,0.f,0.f,0.f};
  f32x4 acc2 = (f32x4){0.f,0.f,0.f,0.f};

  const int arow = mhalf * 16 + l16;
  const _Float16* abase = xs + (size_t)arow * 1024;
  const int akey = arow & 7;
  const _Float16* wbase = WtF + ((size_t)(ngrp * 3) * 64 + lane) * 8;

  #pragma unroll 4
  for (int kstep = 0; kstep < 32; ++kstep) {
    f16x8 a = *(const f16x8*)(abase + (((kstep * 4 + quad) ^ akey) << 3));
    const _Float16* wk = wbase + (size_t)kstep * (12 * 64 * 8);
    f16x8 b0 = *(const f16x8*)(wk);
    f16x8 b1 = *(const f16x8*)(wk + 512);
    f16x8 b2 = *(const f16x8*)(wk + 1024);
    acc0 = __builtin_amdgcn_mfma_f32_16x16x32_f16(a, b0, acc0, 0, 0, 0);
    acc1 = __builtin_amdgcn_mfma_f32_16x16x32_f16(a, b1, acc1, 0, 0, 0);
    acc2 = __builtin_amdgcn_mfma_f32_16x16x32_f16(a, b2, acc2, 0, 0, 0);
  }

  // --- epilogue: C/D col=lane&15, row=quad*4+r. Bias add, f16 write.
  f32x4 accs[3] = {acc0, acc1, acc2};
  #pragma unroll
  for (int i = 0; i < 3; ++i) {
    int nt  = ngrp * 3 + i;
    int col = nt * 16 + l16;
    float bias = (nt < 4) ? bq[col] : (nt < 8) ? bk[col - 64] : bv[col - 128];
    #pragma unroll
    for (int r = 0; r < 4; ++r) {
      int m = m0 + mhalf * 16 + quad * 4 + r;  // global row = b*2048+s
      _Float16 hv = (_Float16)(accs[i][r] + bias);
      if (nt < 4)      qo[(size_t)m * 64 + col] = hv;
      else if (nt < 8) ko[(size_t)m * 64 + (col - 64)] = hv;
      else {                                   // v stored transposed: vt[b][d][s]
        int b = m >> 11, s = m & 2047;
        vt[((size_t)b * 64 + (col - 128)) * 2048 + s] = hv;
      }
    }
  }
}

// ---------------------------------------------------------------------------
// Kernel 3a: attention PARTIALS, flattened split-KV, locality-remapped.
// ROUND 9: force memory-level parallelism. r8 proved cache locality is fine
// (FETCH 3.15MB) yet dur stayed 45.8us with VGPR_Count=52: the scheduler
// sinks each load to just before its MFMA -> ~34 serialized ~600cy L2/L3
// round-trips per wave (= the invariant ~20K-cycle wave lifetime).
// Fix: (a) batch-issue all 16 K loads then sched_barrier(0) so they cannot
// sink -> ONE drain instead of 16; (b) same for the 16 V loads, issued after
// QK (kf dead, regs recycle), drain hidden under softmax+P-write+fence;
// (c) body is branch-free for ALL waves: tail waves simply over-load K/V
// rows beyond kvlen (memory-safe: kv0+128 <= 2048) and the diagonal mask
// already zeroes those scores (exp2(-huge)=0 in PV).
__global__ __launch_bounds__(256, 3) void attn_part(const _Float16* __restrict__ q,
                                                    const _Float16* __restrict__ k,
                                                    const _Float16* __restrict__ vt,
                                                    float* __restrict__ po,
                                                    float* __restrict__ pml) {
  const int tid  = threadIdx.x;
  const int wave = tid >> 6, lane = tid & 63;
  const int l16  = lane & 15, quad = lane >> 4;
  const int x    = blockIdx.x;                 // 0..2175
  const int b    = x & 7;                      // batch == writer XCD slot
  const int j    = x >> 3;                     // 0..271

  // ---- decode j -> (c, u): largest c in [0,15] with c*(33-c) <= j ----
  int lo = 0, hi = 15;
  while (lo < hi) {                            // 4-step exact binary search
    int mid = (lo + hi + 1) >> 1;
    if (mid * (33 - mid) <= j) lo = mid; else hi = mid - 1;
  }
  const int c    = lo;
  const int u    = j - c * (33 - c);           // 0..(32-2c)-1
  const int rel  = 4 * u + wave;               // q-tile offset within chunk's range
  const int qt   = 8 * c + rel;                // 0..127
  const int q0   = qt * 16;
  const int kv0  = c * 128;
  const int item = (x << 2) | wave;            // output slot

  // ---- P/ob overlay: 4352 B per wave (safe: ob writes depend on P reads) ----
  __shared__ __align__(16) unsigned char sbuf[4][4352];
  _Float16 (*P)[136] = (_Float16 (*)[136])&sbuf[wave][0];   // [16][136]
  float    (*ob)[68] = (float    (*)[68])&sbuf[wave][0];    // [16][68]

  const _Float16* qb = q  + (size_t)b * 2048 * 64;
  const _Float16* kb = k  + (size_t)b * 2048 * 64;
  const _Float16* vb = vt + (size_t)b * 64 * 2048;

  f16x8 qf0 = *(const f16x8*)&qb[(q0 + l16) * 64 + quad * 8];
  f16x8 qf1 = *(const f16x8*)&qb[(q0 + l16) * 64 + 32 + quad * 8];

  const float L2E = 1.44269504088896340736f;
  const int qrow  = q0 + l16;

  // ---- K: batch-issue ALL 16 loads, then pin with sched_barrier ----
  f16x8 kf[8][2];
  #pragma unroll
  for (int t = 0; t < 8; ++t) {
    kf[t][0] = *(const f16x8*)&kb[(kv0 + t * 16 + l16) * 64 + quad * 8];
    kf[t][1] = *(const f16x8*)&kb[(kv0 + t * 16 + l16) * 64 + 32 + quad * 8];
  }
  __builtin_amdgcn_sched_barrier(0);           // loads cannot sink past here

  // ---- QK^T (swapped): sc[t][r] = S[kv0+t*16+quad*4+r][q0+l16] ----
  f32x4 sc[8];
  #pragma unroll
  for (int t = 0; t < 8; ++t) {
    const int kvc = kv0 + t * 16;
    f32x4 cc = (f32x4){0.f, 0.f, 0.f, 0.f};
    cc = __builtin_amdgcn_mfma_f32_16x16x32_f16(kf[t][0], qf0, cc, 0, 0, 0);
    cc = __builtin_amdgcn_mfma_f32_16x16x32_f16(kf[t][1], qf1, cc, 0, 0, 0);
    if (kvc + 15 > q0) {                       // diagonal + beyond: mask
      #pragma unroll
      for (int rr2 = 0; rr2 < 4; ++rr2)
        if (kvc + quad * 4 + rr2 > qrow) cc[rr2] = -1e30f;
    }
    sc[t] = cc;
  }

  // ---- V: batch-issue ALL 16 loads (kf dead -> regs recycle), pin ----
  __builtin_amdgcn_sched_barrier(0);           // V loads cannot hoist into QK
  f16x8 vf[4][4];
  #pragma unroll
  for (int ks = 0; ks < 4; ++ks)
    #pragma unroll
    for (int dt = 0; dt < 4; ++dt)
      vf[ks][dt] = *(const f16x8*)&vb[(size_t)(dt * 16 + l16) * 2048 + kv0 + ks * 32 + quad * 8];
  __builtin_amdgcn_sched_barrier(0);           // V loads cannot sink past here
  // drain hides under softmax + P-write + lgkm fence below

  // ---- plain softmax over this chunk (single pass; merge does LSE) ----
  float mx = -1e30f;
  #pragma unroll
  for (int t = 0; t < 8; ++t)
    mx = fmaxf(mx, fmaxf(fmaxf(sc[t][0], sc[t][1]), fmaxf(sc[t][2], sc[t][3])));
  mx = fmaxf(mx, __shfl_xor(mx, 16, 64));
  mx = fmaxf(mx, __shfl_xor(mx, 32, 64));
  const float m = mx;                          // finite: kv0 <= qrow always

  float s = 0.f;
  #pragma unroll
  for (int t = 0; t < 8; ++t) {
    #pragma unroll
    for (int rr2 = 0; rr2 < 4; ++rr2) sc[t][rr2] = exp2f((sc[t][rr2] - m) * L2E);
    s += (sc[t][0] + sc[t][1]) + (sc[t][2] + sc[t][3]);
  }
  s += __shfl_xor(s, 16, 64);
  s += __shfl_xor(s, 32, 64);
  const float l = s;

  // ---- P^T -> LDS in B-frag orientation (b64 writes), drain lgkm ----
  #pragma unroll
  for (int t = 0; t < 8; ++t) {
    f16x4 ph;
    #pragma unroll
    for (int rr2 = 0; rr2 < 4; ++rr2) ph[rr2] = (_Float16)sc[t][rr2];
    *(f16x4*)&P[l16][t * 16 + quad * 4] = ph;
  }
  asm volatile("s_waitcnt lgkmcnt(0)" ::: "memory");

  // ---- PV: o[d][q] += V^T-frag x P^T-frag ----
  f32x4 o[4];
  #pragma unroll
  for (int i = 0; i < 4; ++i) o[i] = (f32x4){0.f, 0.f, 0.f, 0.f};
  #pragma unroll
  for (int ks = 0; ks < 4; ++ks) {
    f16x8 pf = *(const f16x8*)&P[l16][ks * 32 + quad * 8];
    #pragma unroll
    for (int dt = 0; dt < 4; ++dt)
      o[dt] = __builtin_amdgcn_mfma_f32_16x16x32_f16(vf[ks][dt], pf, o[dt], 0, 0, 0);
  }

  // ---- publish: o row=d=dt*16+quad*4+r, col=q=l16 -> LDS transpose ----
  #pragma unroll
  for (int dt = 0; dt < 4; ++dt)
    *(f32x4*)&ob[l16][dt * 16 + quad * 4] = o[dt];
  if (quad == 0) {
    pml[(size_t)item * 32 + l16]      = m;
    pml[(size_t)item * 32 + 16 + l16] = l;
  }
  asm volatile("s_waitcnt lgkmcnt(0)" ::: "memory");
  {
    // coalesced 4KB store: lane -> row = lane>>2 (q), 16 floats of d
    const int row = lane >> 2, c4 = (lane & 3) * 16;
    float* dst = po + (size_t)item * 1024 + row * 64 + c4;
    #pragma unroll
    for (int jj = 0; jj < 4; ++jj)
      *(f32x4*)&dst[jj * 4] = *(const f32x4*)&ob[row][c4 + jj * 4];
  }
}

// ---------------------------------------------------------------------------
// Kernel 3b: merge partials per (b, qt): n = qt/8 + 1 chunks, LSE weighting.
// item(b,qt,c) = (((c*(33-c) + (qt-8c)/4) * 8 + b) << 2) | ((qt-8c)&3).
__global__ __launch_bounds__(256) void attn_merge(const float* __restrict__ po,
                                                  const float* __restrict__ pml,
                                                  float* __restrict__ out) {
  const int blk = blockIdx.x;
  const int b   = blk >> 7, qt = blk & 127;
  const int n   = (qt >> 3) + 1;               // chunks c = 0..qt/8
  const int t   = threadIdx.x;
  const int qr  = t >> 4, d0 = (t & 15) * 4;
  const float L2E = 1.44269504088896340736f;

  int items[16];
  #pragma unroll 4
  for (int c = 0; c < n; ++c) {
    int rel = qt - 8 * c;
    items[c] = (((c * (33 - c) + (rel >> 2)) * 8 + b) << 2) | (rel & 3);
  }

  float M = -1e30f;
  for (int it = 0; it < n; ++it)
    M = fmaxf(M, pml[(size_t)items[it] * 32 + qr]);

  float L = 0.f;
  f32x4 acc = (f32x4){0.f, 0.f, 0.f, 0.f};
  for (int it = 0; it < n; ++it) {
    const float* mlp = pml + (size_t)items[it] * 32;
    float w = exp2f((mlp[qr] - M) * L2E);
    L += w * mlp[16 + qr];
    f32x4 p = *(const f32x4*)&po[((size_t)items[it] * 16 + qr) * 64 + d0];
    #pragma unroll
    for (int jj = 0; jj < 4; ++jj) acc[jj] += w * p[jj];
  }
  const float inv = 1.0f / (L * 32.0f);        // sqrt(H)=32 applied AFTER softmax
  f32x4 res;
  #pragma unroll
  for (int jj = 0; jj < 4; ++jj) res[jj] = acc[jj] * inv;
  *(f32x4*)&out[((size_t)b * 2048 + qt * 16 + qr) * 64 + d0] = res;
}

// ---------------------------------------------------------------------------
extern "C" void kernel_launch(void* const* d_in, const int* in_sizes, int n_in,
                              void* d_out, int out_size, void* d_ws, size_t ws_size,
                              hipStream_t stream) {
  const float* x  = (const float*)d_in[0];
  const float* Wq = (const float*)d_in[1];
  const float* bq = (const float*)d_in[2];
  const float* Wk = (const float*)d_in[3];
  const float* bk = (const float*)d_in[4];
  const float* Wv = (const float*)d_in[5];
  const float* bv = (const float*)d_in[6];
  float* out = (float*)d_out;

  // ws layout: f16 region: WtF 192*1024 | q 16384*64 | k 16384*64 | vt 8*64*2048
  // then f32 region: po 8704*1024 (35.7MB) | pml 8704*32 (1.1MB). Total ~44MB.
  _Float16* WtF = (_Float16*)d_ws;
  _Float16* qo  = WtF + 192 * 1024;
  _Float16* ko  = qo + 16384 * 64;
  _Float16* vt  = ko + 16384 * 64;
  float*    po  = (float*)(vt + 8 * 64 * 2048);
  float*    pml = po + (size_t)8704 * 1024;

  hipLaunchKernelGGL(wt_prep,    dim3(48),   dim3(256), 0, stream, Wq, Wk, Wv, WtF);
  hipLaunchKernelGGL(qkv_gemm,   dim3(512),  dim3(512), 0, stream, x, WtF, bq, bk, bv, qo, ko, vt);
  hipLaunchKernelGGL(attn_part,  dim3(2176), dim3(256), 0, stream, qo, ko, vt, po, pml);
  hipLaunchKernelGGL(attn_merge, dim3(1024), dim3(256), 0, stream, po, pml, out);
}

// Round 10
// 150.778 us; speedup vs baseline: 1.1531x; 1.1531x over previous
//
#include <hip/hip_runtime.h>

// Problem: B=8, S=2048, H=1024, D=64. fp32 in, fp32 out.
// out = softmax_causal(q k^T) / sqrt(H) @ v   (softmax FIRST, then /32)

typedef float     f32x4 __attribute__((ext_vector_type(4)));
typedef _Float16  f16x8 __attribute__((ext_vector_type(8)));
typedef _Float16  f16x4 __attribute__((ext_vector_type(4)));

// ---------------------------------------------------------------------------
// Kernel 1: pack W{q,k,v} into MFMA B-fragment order (f16) via LDS transpose.
__global__ __launch_bounds__(256) void wt_prep(const float* __restrict__ Wq,
                                               const float* __restrict__ Wk,
                                               const float* __restrict__ Wv,
                                               _Float16* __restrict__ WtF) {
  const int w  = blockIdx.x >> 4;              // which W
  const int kt = blockIdx.x & 15;              // k-tile of 64
  const float* src = (w == 0) ? Wq : (w == 1 ? Wk : Wv);
  __shared__ _Float16 ls[64][72];              // [local k][n], padded
  const int t = threadIdx.x;
  {
    int rr = t >> 4;                           // 0..15
    int c4 = (t & 15) * 4;
    #pragma unroll
    for (int ri = 0; ri < 4; ++ri) {
      int k = rr + ri * 16;                    // local k 0..63
      f32x4 f = *(const f32x4*)&src[(size_t)(kt * 64 + k) * 64 + c4];
      #pragma unroll
      for (int j = 0; j < 4; ++j) ls[k][c4 + j] = (_Float16)f[j];
    }
  }
  __syncthreads();
  const int lane = t & 63, l16 = lane & 15, quad = lane >> 4;
  #pragma unroll
  for (int h = 0; h < 2; ++h) {
    int fid     = h * 4 + (t >> 6);            // 0..7
    int kstep_l = fid >> 2;                    // 0..1
    int ntl     = fid & 3;                     // 0..3
    int nt      = w * 4 + ntl;
    int kstep   = kt * 2 + kstep_l;
    f16x8 o;
    #pragma unroll
    for (int j = 0; j < 8; ++j) o[j] = ls[kstep_l * 32 + quad * 8 + j][ntl * 16 + l16];
    *(f16x8*)&WtF[((size_t)(kstep * 12 + nt) * 64 + lane) * 8] = o;
  }
}

// ---------------------------------------------------------------------------
// Kernel 2: QKV projection. XCD-aligned block remap kept (batch = bid&7) --
// affinity partner of attn's b = blockIdx&7.
__global__ __launch_bounds__(512, 4) void qkv_gemm(const float* __restrict__ x,
                                                   const _Float16* __restrict__ WtF,
                                                   const float* __restrict__ bq,
                                                   const float* __restrict__ bk,
                                                   const float* __restrict__ bv,
                                                   _Float16* __restrict__ qo,
                                                   _Float16* __restrict__ ko,
                                                   _Float16* __restrict__ vt) {
  __shared__ _Float16 xs[32 * 1024];           // exactly 64 KB
  const int tid  = threadIdx.x;
  const int wave = tid >> 6, lane = tid & 63;
  const int l16  = lane & 15, quad = lane >> 4;
  const int mhalf = wave >> 2;                 // 0..1
  const int ngrp  = wave & 3;                  // 0..3
  const int bid   = blockIdx.x;
  const int m0    = (((bid & 7) << 6) + (bid >> 3)) * 32;  // batch=bid&7, tile=bid>>3

  // --- stage x tile (fp32 -> f16), coalesced: 16-lane groups read 256B runs
  {
    int row   = tid >> 4;                      // 0..31
    int cbase = (tid & 15) * 4;
    const float* xrow = x + (size_t)(m0 + row) * 1024;
    int key = row & 7;
    #pragma unroll
    for (int j = 0; j < 16; ++j) {
      int col = cbase + j * 64;
      f32x4 f = *(const f32x4*)&xrow[col];
      f16x4 hh;
      #pragma unroll
      for (int e = 0; e < 4; ++e) hh[e] = (_Float16)f[e];
      int g   = col >> 3;                      // granule index 0..127
      int sub = col & 7;                       // 0 or 4
      *(f16x4*)&xs[(size_t)row * 1024 + (size_t)((g ^ key) << 3) + sub] = hh;
    }
  }
  __syncthreads();

  f32x4 acc0 = (f32x4){0.f,0.f,0.f,0.f};
  f32x4 acc1 = (f32x4){0.f,0.f,0.f,0.f};
  f32x4 acc2 = (f32x4){0.f,0.f,0.f,0.f};

  const int arow = mhalf * 16 + l16;
  const _Float16* abase = xs + (size_t)arow * 1024;
  const int akey = arow & 7;
  const _Float16* wbase = WtF + ((size_t)(ngrp * 3) * 64 + lane) * 8;

  #pragma unroll 4
  for (int kstep = 0; kstep < 32; ++kstep) {
    f16x8 a = *(const f16x8*)(abase + (((kstep * 4 + quad) ^ akey) << 3));
    const _Float16* wk = wbase + (size_t)kstep * (12 * 64 * 8);
    f16x8 b0 = *(const f16x8*)(wk);
    f16x8 b1 = *(const f16x8*)(wk + 512);
    f16x8 b2 = *(const f16x8*)(wk + 1024);
    acc0 = __builtin_amdgcn_mfma_f32_16x16x32_f16(a, b0, acc0, 0, 0, 0);
    acc1 = __builtin_amdgcn_mfma_f32_16x16x32_f16(a, b1, acc1, 0, 0, 0);
    acc2 = __builtin_amdgcn_mfma_f32_16x16x32_f16(a, b2, acc2, 0, 0, 0);
  }

  // --- epilogue: C/D col=lane&15, row=quad*4+r. Bias add, f16 write.
  f32x4 accs[3] = {acc0, acc1, acc2};
  #pragma unroll
  for (int i = 0; i < 3; ++i) {
    int nt  = ngrp * 3 + i;
    int col = nt * 16 + l16;
    float bias = (nt < 4) ? bq[col] : (nt < 8) ? bk[col - 64] : bv[col - 128];
    #pragma unroll
    for (int r = 0; r < 4; ++r) {
      int m = m0 + mhalf * 16 + quad * 4 + r;  // global row = b*2048+s
      _Float16 hv = (_Float16)(accs[i][r] + bias);
      if (nt < 4)      qo[(size_t)m * 64 + col] = hv;
      else if (nt < 8) ko[(size_t)m * 64 + (col - 64)] = hv;
      else {                                   // v stored transposed: vt[b][d][s]
        int b = m >> 11, s = m & 2047;
        vt[((size_t)b * 64 + (col - 128)) * 2048 + s] = hv;
      }
    }
  }
}

// ---------------------------------------------------------------------------
// Kernel 3: causal attention -- LOOPED per-wave flash, register double-buffer.
// r6-r9 falsified everything about one-shot waves (VALU, balance, locality,
// sched pinning): each short wave pays ~full load latency per 128 kv. Now:
// 512 blocks x 4 waves = 2048 waves = exactly 2/SIMD, all resident, no
// turnover. Block (b, pair): q-tiles qtA=pair, qtB=127-pair (uniform work);
// wave w: q-tile (w>>1), contiguous kv-half (w&1) -> <=16 tiles of 64 kv per
// wave. Per tile: 16 global loads into STATIC A/B reg buffers (rule #20),
// next tile's loads issued before current tile's compute (MFMA+softmax+P
// roundtrip ~500cy hides the drain). Online softmax per lane (swapped QK).
// In-block 2-way LSE merge (r2 machinery). No split-KV globals, no merge
// kernel. VGPR ~184 under (256,2)=cap 256: no spill.
__global__ __launch_bounds__(256, 2) void attn(const _Float16* __restrict__ q,
                                               const _Float16* __restrict__ k,
                                               const _Float16* __restrict__ vt,
                                               float* __restrict__ out) {
  const int blk  = blockIdx.x;
  const int pair = blk >> 3;                   // 0..63
  const int b    = blk & 7;                    // batch == writer XCD slot
  const int tid  = threadIdx.x;
  const int w    = tid >> 6, lane = tid & 63;
  const int l16  = lane & 15, quad = lane >> 4;
  const int whichq = w >> 1;                   // 0: qtA, 1: qtB
  const int half   = w & 1;                    // kv-half within the q-tile
  const int qt   = whichq ? (127 - pair) : pair;
  const int q0   = qt * 16;
  const int qrow = q0 + l16;
  const int nt   = (qt >> 2) + 1;              // kv tiles of 64 (ceil((q0+16)/64))
  const int nh0  = (nt + 1) >> 1;
  const int t0   = half ? nh0 : 0;
  const int t1   = half ? nt : nh0;

  // per-wave P (f16[16][72], 2304B) overlaid with ob (f32[16][68], 4352B)
  __shared__ __align__(16) unsigned char sbuf[4][4352];
  __shared__ float mlb[4][2][16];
  _Float16 (*Pw)[72]  = (_Float16 (*)[72])&sbuf[w][0];
  float    (*obw)[68] = (float    (*)[68])&sbuf[w][0];

  const _Float16* qb = q  + (size_t)b * 2048 * 64;
  const _Float16* kb = k  + (size_t)b * 2048 * 64;
  const _Float16* vb = vt + (size_t)b * 64 * 2048;

  const f16x8 qf0 = *(const f16x8*)&qb[(q0 + l16) * 64 + quad * 8];
  const f16x8 qf1 = *(const f16x8*)&qb[(q0 + l16) * 64 + 32 + quad * 8];

  const float L2E = 1.44269504088896340736f;
  float m = -1e30f, l = 0.f;
  f32x4 o_[4];
  #pragma unroll
  for (int i = 0; i < 4; ++i) o_[i] = (f32x4){0.f, 0.f, 0.f, 0.f};

  // static double buffers (rule #20: no runtime indexing)
  f16x8 kfA[4][2], kfB[4][2], vfA[2][4], vfB[2][4];

  auto LOADT = [&](f16x8 (&kf)[4][2], f16x8 (&vf)[2][4], int t) {
    const int kvb = t * 64;
    #pragma unroll
    for (int st = 0; st < 4; ++st) {
      kf[st][0] = *(const f16x8*)&kb[(kvb + st * 16 + l16) * 64 + quad * 8];
      kf[st][1] = *(const f16x8*)&kb[(kvb + st * 16 + l16) * 64 + 32 + quad * 8];
    }
    #pragma unroll
    for (int ks = 0; ks < 2; ++ks)
      #pragma unroll
      for (int dt = 0; dt < 4; ++dt)
        vf[ks][dt] = *(const f16x8*)&vb[(size_t)(dt * 16 + l16) * 2048 + kvb + ks * 32 + quad * 8];
  };

  auto COMPUTE = [&](const f16x8 (&kf)[4][2], const f16x8 (&vf)[2][4], int t) {
    const int kvb = t * 64;
    // QK^T (swapped): sc[st][r] = S[kvb+st*16+quad*4+r][q0+l16]
    f32x4 sc[4];
    #pragma unroll
    for (int st = 0; st < 4; ++st) {
      f32x4 cc = (f32x4){0.f, 0.f, 0.f, 0.f};
      cc = __builtin_amdgcn_mfma_f32_16x16x32_f16(kf[st][0], qf0, cc, 0, 0, 0);
      cc = __builtin_amdgcn_mfma_f32_16x16x32_f16(kf[st][1], qf1, cc, 0, 0, 0);
      sc[st] = cc;
    }
    if (kvb + 63 > q0) {                       // diagonal tile: causal mask
      #pragma unroll
      for (int st = 0; st < 4; ++st)
        #pragma unroll
        for (int r = 0; r < 4; ++r)
          if (kvb + st * 16 + quad * 4 + r > qrow) sc[st][r] = -1e30f;
    }
    // online softmax: per-lane over 16 kv + 2 quad shuffles
    float mx = -1e30f;
    #pragma unroll
    for (int st = 0; st < 4; ++st)
      mx = fmaxf(mx, fmaxf(fmaxf(sc[st][0], sc[st][1]), fmaxf(sc[st][2], sc[st][3])));
    mx = fmaxf(mx, __shfl_xor(mx, 16, 64));
    mx = fmaxf(mx, __shfl_xor(mx, 32, 64));
    const float mnew  = fmaxf(m, mx);
    const float alpha = exp2f((m - mnew) * L2E);
    m = mnew;
    float s = 0.f;
    #pragma unroll
    for (int st = 0; st < 4; ++st) {
      #pragma unroll
      for (int r = 0; r < 4; ++r) sc[st][r] = exp2f((sc[st][r] - m) * L2E);
      s += (sc[st][0] + sc[st][1]) + (sc[st][2] + sc[st][3]);
    }
    s += __shfl_xor(s, 16, 64);
    s += __shfl_xor(s, 32, 64);
    l = l * alpha + s;
    #pragma unroll
    for (int dt = 0; dt < 4; ++dt)
      #pragma unroll
      for (int r = 0; r < 4; ++r) o_[dt][r] *= alpha;
    // P^T -> per-wave LDS (B-frag orientation), fence, PV
    #pragma unroll
    for (int st = 0; st < 4; ++st) {
      f16x4 ph;
      #pragma unroll
      for (int r = 0; r < 4; ++r) ph[r] = (_Float16)sc[st][r];
      *(f16x4*)&Pw[l16][st * 16 + quad * 4] = ph;
    }
    asm volatile("s_waitcnt lgkmcnt(0)" ::: "memory");
    __builtin_amdgcn_sched_barrier(0);
    #pragma unroll
    for (int ks = 0; ks < 2; ++ks) {
      f16x8 pf = *(const f16x8*)&Pw[l16][ks * 32 + quad * 8];
      #pragma unroll
      for (int dt = 0; dt < 4; ++dt)
        o_[dt] = __builtin_amdgcn_mfma_f32_16x16x32_f16(vf[ks][dt], pf, o_[dt], 0, 0, 0);
    }
  };

  // software-pipelined kv loop: load t+1 before computing t
  int t = t0;
  if (t < t1) {
    LOADT(kfA, vfA, t);
    while (t + 1 < t1) {
      LOADT(kfB, vfB, t + 1);
      __builtin_amdgcn_sched_barrier(0);
      COMPUTE(kfA, vfA, t);
      if (t + 2 < t1) {
        LOADT(kfA, vfA, t + 2);
        __builtin_amdgcn_sched_barrier(0);
      }
      COMPUTE(kfB, vfB, t + 1);
      t += 2;
    }
    if (t < t1) COMPUTE(kfA, vfA, t);
  }

  // publish per-wave partials: obw[q][d] = O[d][q]^T, (m,l) per q-row
  #pragma unroll
  for (int dt = 0; dt < 4; ++dt)
    *(f32x4*)&obw[l16][dt * 16 + quad * 4] = o_[dt];
  if (quad == 0) {
    mlb[w][0][l16] = m;
    mlb[w][1][l16] = l;
  }
  __syncthreads();

  // 2-way LSE merge per q-tile: waves (0,1) -> qtA, (2,3) -> qtB
  {
    const int grp = tid >> 7;                  // 0: qtA, 1: qtB
    const int idx = tid & 127;
    const int row = idx >> 3;
    const int c8  = (idx & 7) * 8;
    const int wb  = grp * 2;
    const int qtg = grp ? (127 - pair) : pair;
    const float m0v = mlb[wb][0][row], m1v = mlb[wb + 1][0][row];
    const float M   = fmaxf(m0v, m1v);
    const float w0  = exp2f((m0v - M) * L2E);
    const float w1  = exp2f((m1v - M) * L2E);
    const float L   = w0 * mlb[wb][1][row] + w1 * mlb[wb + 1][1][row];
    const float inv = 1.0f / (L * 32.0f);      // sqrt(H)=32 applied AFTER softmax
    const float (*oA)[68] = (const float (*)[68])&sbuf[wb][0];
    const float (*oB)[68] = (const float (*)[68])&sbuf[wb + 1][0];
    float* dst = out + ((size_t)b * 2048 + qtg * 16 + row) * 64 + c8;
    #pragma unroll
    for (int j = 0; j < 2; ++j) {
      f32x4 a = *(const f32x4*)&oA[row][c8 + j * 4];
      f32x4 bb = *(const f32x4*)&oB[row][c8 + j * 4];
      f32x4 r;
      #pragma unroll
      for (int e = 0; e < 4; ++e) r[e] = (w0 * a[e] + w1 * bb[e]) * inv;
      *(f32x4*)&dst[j * 4] = r;
    }
  }
}

// ---------------------------------------------------------------------------
extern "C" void kernel_launch(void* const* d_in, const int* in_sizes, int n_in,
                              void* d_out, int out_size, void* d_ws, size_t ws_size,
                              hipStream_t stream) {
  const float* x  = (const float*)d_in[0];
  const float* Wq = (const float*)d_in[1];
  const float* bq = (const float*)d_in[2];
  const float* Wk = (const float*)d_in[3];
  const float* bk = (const float*)d_in[4];
  const float* Wv = (const float*)d_in[5];
  const float* bv = (const float*)d_in[6];
  float* out = (float*)d_out;

  // ws layout (f16): WtF 192*1024 | q 16384*64 | k 16384*64 | vt 8*64*2048
  _Float16* WtF = (_Float16*)d_ws;
  _Float16* qo  = WtF + 192 * 1024;
  _Float16* ko  = qo + 16384 * 64;
  _Float16* vt  = ko + 16384 * 64;

  hipLaunchKernelGGL(wt_prep,  dim3(48),  dim3(256), 0, stream, Wq, Wk, Wv, WtF);
  hipLaunchKernelGGL(qkv_gemm, dim3(512), dim3(512), 0, stream, x, WtF, bq, bk, bv, qo, ko, vt);
  hipLaunchKernelGGL(attn,     dim3(512), dim3(256), 0, stream, qo, ko, vt, out);
}

// Round 11
// 135.868 us; speedup vs baseline: 1.2796x; 1.1097x over previous
//
#include <hip/hip_runtime.h>

// Problem: B=8, S=2048, H=1024, D=64. fp32 in, fp32 out.
// out = softmax_causal(q k^T) / sqrt(H) @ v   (softmax FIRST, then /32)

typedef float     f32x4 __attribute__((ext_vector_type(4)));
typedef _Float16  f16x8 __attribute__((ext_vector_type(8)));
typedef _Float16  f16x4 __attribute__((ext_vector_type(4)));

// ---------------------------------------------------------------------------
// Kernel 1: pack W{q,k,v} into MFMA B-fragment order (f16) via LDS transpose.
__global__ __launch_bounds__(256) void wt_prep(const float* __restrict__ Wq,
                                               const float* __restrict__ Wk,
                                               const float* __restrict__ Wv,
                                               _Float16* __restrict__ WtF) {
  const int w  = blockIdx.x >> 4;              // which W
  const int kt = blockIdx.x & 15;              // k-tile of 64
  const float* src = (w == 0) ? Wq : (w == 1 ? Wk : Wv);
  __shared__ _Float16 ls[64][72];              // [local k][n], padded
  const int t = threadIdx.x;
  {
    int rr = t >> 4;                           // 0..15
    int c4 = (t & 15) * 4;
    #pragma unroll
    for (int ri = 0; ri < 4; ++ri) {
      int k = rr + ri * 16;                    // local k 0..63
      f32x4 f = *(const f32x4*)&src[(size_t)(kt * 64 + k) * 64 + c4];
      #pragma unroll
      for (int j = 0; j < 4; ++j) ls[k][c4 + j] = (_Float16)f[j];
    }
  }
  __syncthreads();
  const int lane = t & 63, l16 = lane & 15, quad = lane >> 4;
  #pragma unroll
  for (int h = 0; h < 2; ++h) {
    int fid     = h * 4 + (t >> 6);            // 0..7
    int kstep_l = fid >> 2;                    // 0..1
    int ntl     = fid & 3;                     // 0..3
    int nt      = w * 4 + ntl;
    int kstep   = kt * 2 + kstep_l;
    f16x8 o;
    #pragma unroll
    for (int j = 0; j < 8; ++j) o[j] = ls[kstep_l * 32 + quad * 8 + j][ntl * 16 + l16];
    *(f16x8*)&WtF[((size_t)(kstep * 12 + nt) * 64 + lane) * 8] = o;
  }
}

// ---------------------------------------------------------------------------
// Kernel 2: QKV projection. ROUND 11: epilogue writes Q/K/V in MFMA
// FRAGMENT ORDER so attn's loads are lane-contiguous 1KB bursts (8 cache
// lines/load instead of 16 divergent 64B segments -- the address-divergence
// theory for attn's invariant ~35us). Layouts (per batch b):
//   qfr[(b*128+qt)*2+h][lane][j] = Q[b][qt*16+(lane&15)][h*32+(lane>>4)*8+j]
//   kfr[(b*128+kt)*2+h][lane][j] = K[b][kt*16+(lane&15)][h*32+(lane>>4)*8+j]
//   vfr[(b*64+ks)*4+dt][lane][j] = V[b][ks*32+(lane>>4)*8+j][dt*16+(lane&15)]
// XCD-aligned block remap kept (batch = bid&7).
__global__ __launch_bounds__(512, 4) void qkv_gemm(const float* __restrict__ x,
                                                   const _Float16* __restrict__ WtF,
                                                   const float* __restrict__ bq,
                                                   const float* __restrict__ bk,
                                                   const float* __restrict__ bv,
                                                   _Float16* __restrict__ qfr,
                                                   _Float16* __restrict__ kfr,
                                                   _Float16* __restrict__ vfr) {
  __shared__ _Float16 xs[32 * 1024];           // exactly 64 KB
  const int tid  = threadIdx.x;
  const int wave = tid >> 6, lane = tid & 63;
  const int l16  = lane & 15, quad = lane >> 4;
  const int mhalf = wave >> 2;                 // 0..1
  const int ngrp  = wave & 3;                  // 0..3
  const int bid   = blockIdx.x;
  const int m0    = (((bid & 7) << 6) + (bid >> 3)) * 32;  // batch=bid&7, tile=bid>>3

  // --- stage x tile (fp32 -> f16), coalesced: 16-lane groups read 256B runs
  {
    int row   = tid >> 4;                      // 0..31
    int cbase = (tid & 15) * 4;
    const float* xrow = x + (size_t)(m0 + row) * 1024;
    int key = row & 7;
    #pragma unroll
    for (int j = 0; j < 16; ++j) {
      int col = cbase + j * 64;
      f32x4 f = *(const f32x4*)&xrow[col];
      f16x4 hh;
      #pragma unroll
      for (int e = 0; e < 4; ++e) hh[e] = (_Float16)f[e];
      int g   = col >> 3;                      // granule index 0..127
      int sub = col & 7;                       // 0 or 4
      *(f16x4*)&xs[(size_t)row * 1024 + (size_t)((g ^ key) << 3) + sub] = hh;
    }
  }
  __syncthreads();

  f32x4 acc0 = (f32x4){0.f,0.f,0.f,0.f};
  f32x4 acc1 = (f32x4){0.f,0.f,0.f,0.f};
  f32x4 acc2 = (f32x4){0.f,0.f,0.f,0.f};

  const int arow = mhalf * 16 + l16;
  const _Float16* abase = xs + (size_t)arow * 1024;
  const int akey = arow & 7;
  const _Float16* wbase = WtF + ((size_t)(ngrp * 3) * 64 + lane) * 8;

  #pragma unroll 4
  for (int kstep = 0; kstep < 32; ++kstep) {
    f16x8 a = *(const f16x8*)(abase + (((kstep * 4 + quad) ^ akey) << 3));
    const _Float16* wk = wbase + (size_t)kstep * (12 * 64 * 8);
    f16x8 b0 = *(const f16x8*)(wk);
    f16x8 b1 = *(const f16x8*)(wk + 512);
    f16x8 b2 = *(const f16x8*)(wk + 1024);
    acc0 = __builtin_amdgcn_mfma_f32_16x16x32_f16(a, b0, acc0, 0, 0, 0);
    acc1 = __builtin_amdgcn_mfma_f32_16x16x32_f16(a, b1, acc1, 0, 0, 0);
    acc2 = __builtin_amdgcn_mfma_f32_16x16x32_f16(a, b2, acc2, 0, 0, 0);
  }

  // --- epilogue: C/D col=lane&15, row=quad*4+r. Bias add, frag-order write.
  f32x4 accs[3] = {acc0, acc1, acc2};
  #pragma unroll
  for (int i = 0; i < 3; ++i) {
    int nt  = ngrp * 3 + i;
    int col = nt * 16 + l16;
    float bias = (nt < 4) ? bq[col] : (nt < 8) ? bk[col - 64] : bv[col - 128];
    #pragma unroll
    for (int r = 0; r < 4; ++r) {
      int m = m0 + mhalf * 16 + quad * 4 + r;  // global row = b*2048+s
      _Float16 hv = (_Float16)(accs[i][r] + bias);
      if (nt < 4) {
        // Q-frag: ((m>>4)*2 + col>>5)*512 + (((col>>3)&3)*16 + (m&15))*8 + (col&7)
        qfr[((size_t)(m >> 4) * 2 + (col >> 5)) * 512
            + (((col >> 3) & 3) * 16 + (m & 15)) * 8 + (col & 7)] = hv;
      } else if (nt < 8) {
        int ck = col - 64;
        kfr[((size_t)(m >> 4) * 2 + (ck >> 5)) * 512
            + (((ck >> 3) & 3) * 16 + (m & 15)) * 8 + (ck & 7)] = hv;
      } else {
        int cv = col - 128;                    // d
        int b = m >> 11, s = m & 2047;
        vfr[(((size_t)b * 64 + (s >> 5)) * 4 + (cv >> 4)) * 512
            + (((s >> 3) & 3) * 16 + (cv & 15)) * 8 + (s & 7)] = hv;
      }
    }
  }
}

// ---------------------------------------------------------------------------
// Kernel 3: causal attention -- LOOPED per-wave flash (r10 structure kept:
// 512 blocks x 4 waves = 2048 resident waves, complementary q-tile pairing,
// per-wave kv-half, register double-buffer pipeline, online softmax, in-block
// 2-way LSE merge). ROUND 11 change: ALL global loads read the frag-order
// buffers -> *(f16x8*)(base + lane*8): 64 lanes x 16B = 1KB fully contiguous,
// 8 cache lines per load (was 16 divergent 64B segments). Tests the
// address-divergence / TA-throughput theory; everything else identical.
__global__ __launch_bounds__(256, 2) void attn(const _Float16* __restrict__ qfr,
                                               const _Float16* __restrict__ kfr,
                                               const _Float16* __restrict__ vfr,
                                               float* __restrict__ out) {
  const int blk  = blockIdx.x;
  const int pair = blk >> 3;                   // 0..63
  const int b    = blk & 7;                    // batch == writer XCD slot
  const int tid  = threadIdx.x;
  const int w    = tid >> 6, lane = tid & 63;
  const int l16  = lane & 15, quad = lane >> 4;
  const int whichq = w >> 1;                   // 0: qtA, 1: qtB
  const int half   = w & 1;                    // kv-half within the q-tile
  const int qt   = whichq ? (127 - pair) : pair;
  const int q0   = qt * 16;
  const int qrow = q0 + l16;
  const int nt   = (qt >> 2) + 1;              // kv tiles of 64 (ceil((q0+16)/64))
  const int nh0  = (nt + 1) >> 1;
  const int t0   = half ? nh0 : 0;
  const int t1   = half ? nt : nh0;

  // per-wave P (f16[16][72], 2304B) overlaid with ob (f32[16][68], 4352B)
  __shared__ __align__(16) unsigned char sbuf[4][4352];
  __shared__ float mlb[4][2][16];
  _Float16 (*Pw)[72]  = (_Float16 (*)[72])&sbuf[w][0];
  float    (*obw)[68] = (float    (*)[68])&sbuf[w][0];

  // frag-order bases: every load is base + lane*8 (1KB wave-burst)
  const _Float16* qb = qfr + ((size_t)(b * 128 + qt) * 2) * 512 + lane * 8;
  const _Float16* kb = kfr + ((size_t)b * 128 * 2) * 512 + lane * 8;
  const _Float16* vb = vfr + ((size_t)b * 64 * 4) * 512 + lane * 8;

  const f16x8 qf0 = *(const f16x8*)(qb);
  const f16x8 qf1 = *(const f16x8*)(qb + 512);

  const float L2E = 1.44269504088896340736f;
  float m = -1e30f, l = 0.f;
  f32x4 o_[4];
  #pragma unroll
  for (int i = 0; i < 4; ++i) o_[i] = (f32x4){0.f, 0.f, 0.f, 0.f};

  // static double buffers (rule #20: no runtime indexing)
  f16x8 kfA[4][2], kfB[4][2], vfA[2][4], vfB[2][4];

  auto LOADT = [&](f16x8 (&kf)[4][2], f16x8 (&vf)[2][4], int t) {
    // K tile t: frags (t*4+st, h) at offset ((t*4+st)*2+h)*512
    const _Float16* kp = kb + (size_t)t * 4096;
    #pragma unroll
    for (int st = 0; st < 4; ++st) {
      kf[st][0] = *(const f16x8*)(kp + st * 1024);
      kf[st][1] = *(const f16x8*)(kp + st * 1024 + 512);
    }
    // V tile t: frags (t*2+ks, dt) at offset ((t*2+ks)*4+dt)*512
    const _Float16* vp = vb + (size_t)t * 4096;
    #pragma unroll
    for (int ks = 0; ks < 2; ++ks)
      #pragma unroll
      for (int dt = 0; dt < 4; ++dt)
        vf[ks][dt] = *(const f16x8*)(vp + ks * 2048 + dt * 512);
  };

  auto COMPUTE = [&](const f16x8 (&kf)[4][2], const f16x8 (&vf)[2][4], int t) {
    const int kvb = t * 64;
    // QK^T (swapped): sc[st][r] = S[kvb+st*16+quad*4+r][q0+l16]
    f32x4 sc[4];
    #pragma unroll
    for (int st = 0; st < 4; ++st) {
      f32x4 cc = (f32x4){0.f, 0.f, 0.f, 0.f};
      cc = __builtin_amdgcn_mfma_f32_16x16x32_f16(kf[st][0], qf0, cc, 0, 0, 0);
      cc = __builtin_amdgcn_mfma_f32_16x16x32_f16(kf[st][1], qf1, cc, 0, 0, 0);
      sc[st] = cc;
    }
    if (kvb + 63 > q0) {                       // diagonal tile: causal mask
      #pragma unroll
      for (int st = 0; st < 4; ++st)
        #pragma unroll
        for (int r = 0; r < 4; ++r)
          if (kvb + st * 16 + quad * 4 + r > qrow) sc[st][r] = -1e30f;
    }
    // online softmax: per-lane over 16 kv + 2 quad shuffles
    float mx = -1e30f;
    #pragma unroll
    for (int st = 0; st < 4; ++st)
      mx = fmaxf(mx, fmaxf(fmaxf(sc[st][0], sc[st][1]), fmaxf(sc[st][2], sc[st][3])));
    mx = fmaxf(mx, __shfl_xor(mx, 16, 64));
    mx = fmaxf(mx, __shfl_xor(mx, 32, 64));
    const float mnew  = fmaxf(m, mx);
    const float alpha = exp2f((m - mnew) * L2E);
    m = mnew;
    float s = 0.f;
    #pragma unroll
    for (int st = 0; st < 4; ++st) {
      #pragma unroll
      for (int r = 0; r < 4; ++r) sc[st][r] = exp2f((sc[st][r] - m) * L2E);
      s += (sc[st][0] + sc[st][1]) + (sc[st][2] + sc[st][3]);
    }
    s += __shfl_xor(s, 16, 64);
    s += __shfl_xor(s, 32, 64);
    l = l * alpha + s;
    #pragma unroll
    for (int dt = 0; dt < 4; ++dt)
      #pragma unroll
      for (int r = 0; r < 4; ++r) o_[dt][r] *= alpha;
    // P^T -> per-wave LDS (B-frag orientation), fence, PV
    #pragma unroll
    for (int st = 0; st < 4; ++st) {
      f16x4 ph;
      #pragma unroll
      for (int r = 0; r < 4; ++r) ph[r] = (_Float16)sc[st][r];
      *(f16x4*)&Pw[l16][st * 16 + quad * 4] = ph;
    }
    asm volatile("s_waitcnt lgkmcnt(0)" ::: "memory");
    __builtin_amdgcn_sched_barrier(0);
    #pragma unroll
    for (int ks = 0; ks < 2; ++ks) {
      f16x8 pf = *(const f16x8*)&Pw[l16][ks * 32 + quad * 8];
      #pragma unroll
      for (int dt = 0; dt < 4; ++dt)
        o_[dt] = __builtin_amdgcn_mfma_f32_16x16x32_f16(vf[ks][dt], pf, o_[dt], 0, 0, 0);
    }
  };

  // software-pipelined kv loop: load t+1 before computing t
  int t = t0;
  if (t < t1) {
    LOADT(kfA, vfA, t);
    while (t + 1 < t1) {
      LOADT(kfB, vfB, t + 1);
      __builtin_amdgcn_sched_barrier(0);
      COMPUTE(kfA, vfA, t);
      if (t + 2 < t1) {
        LOADT(kfA, vfA, t + 2);
        __builtin_amdgcn_sched_barrier(0);
      }
      COMPUTE(kfB, vfB, t + 1);
      t += 2;
    }
    if (t < t1) COMPUTE(kfA, vfA, t);
  }

  // publish per-wave partials: obw[q][d] = O[d][q]^T, (m,l) per q-row
  #pragma unroll
  for (int dt = 0; dt < 4; ++dt)
    *(f32x4*)&obw[l16][dt * 16 + quad * 4] = o_[dt];
  if (quad == 0) {
    mlb[w][0][l16] = m;
    mlb[w][1][l16] = l;
  }
  __syncthreads();

  // 2-way LSE merge per q-tile: waves (0,1) -> qtA, (2,3) -> qtB
  {
    const int grp = tid >> 7;                  // 0: qtA, 1: qtB
    const int idx = tid & 127;
    const int row = idx >> 3;
    const int c8  = (idx & 7) * 8;
    const int wb  = grp * 2;
    const int qtg = grp ? (127 - pair) : pair;
    const float m0v = mlb[wb][0][row], m1v = mlb[wb + 1][0][row];
    const float M   = fmaxf(m0v, m1v);
    const float w0  = exp2f((m0v - M) * L2E);
    const float w1  = exp2f((m1v - M) * L2E);
    const float L   = w0 * mlb[wb][1][row] + w1 * mlb[wb + 1][1][row];
    const float inv = 1.0f / (L * 32.0f);      // sqrt(H)=32 applied AFTER softmax
    const float (*oA)[68] = (const float (*)[68])&sbuf[wb][0];
    const float (*oB)[68] = (const float (*)[68])&sbuf[wb + 1][0];
    float* dst = out + ((size_t)b * 2048 + qtg * 16 + row) * 64 + c8;
    #pragma unroll
    for (int j = 0; j < 2; ++j) {
      f32x4 a = *(const f32x4*)&oA[row][c8 + j * 4];
      f32x4 bb = *(const f32x4*)&oB[row][c8 + j * 4];
      f32x4 r;
      #pragma unroll
      for (int e = 0; e < 4; ++e) r[e] = (w0 * a[e] + w1 * bb[e]) * inv;
      *(f32x4*)&dst[j * 4] = r;
    }
  }
}

// ---------------------------------------------------------------------------
extern "C" void kernel_launch(void* const* d_in, const int* in_sizes, int n_in,
                              void* d_out, int out_size, void* d_ws, size_t ws_size,
                              hipStream_t stream) {
  const float* x  = (const float*)d_in[0];
  const float* Wq = (const float*)d_in[1];
  const float* bq = (const float*)d_in[2];
  const float* Wk = (const float*)d_in[3];
  const float* bk = (const float*)d_in[4];
  const float* Wv = (const float*)d_in[5];
  const float* bv = (const float*)d_in[6];
  float* out = (float*)d_out;

  // ws layout (f16): WtF 192*1024 | qfr 1M | kfr 1M | vfr 1M  (~6.7MB)
  _Float16* WtF = (_Float16*)d_ws;
  _Float16* qfr = WtF + 192 * 1024;
  _Float16* kfr = qfr + (size_t)8 * 128 * 2 * 512;
  _Float16* vfr = kfr + (size_t)8 * 128 * 2 * 512;

  hipLaunchKernelGGL(wt_prep,  dim3(48),  dim3(256), 0, stream, Wq, Wk, Wv, WtF);
  hipLaunchKernelGGL(qkv_gemm, dim3(512), dim3(512), 0, stream, x, WtF, bq, bk, bv, qfr, kfr, vfr);
  hipLaunchKernelGGL(attn,     dim3(512), dim3(256), 0, stream, qfr, kfr, vfr, out);
}

// Round 12
// 135.056 us; speedup vs baseline: 1.2873x; 1.0060x over previous
//
#include <hip/hip_runtime.h>

// Problem: B=8, S=2048, H=1024, D=64. fp32 in, fp32 out.
// out = softmax_causal(q k^T) / sqrt(H) @ v   (softmax FIRST, then /32)

typedef float     f32x4 __attribute__((ext_vector_type(4)));
typedef _Float16  f16x8 __attribute__((ext_vector_type(8)));
typedef _Float16  f16x4 __attribute__((ext_vector_type(4)));

// ---------------------------------------------------------------------------
// Kernel 1: pack W{q,k,v} into MFMA B-fragment order (f16) via LDS transpose.
__global__ __launch_bounds__(256) void wt_prep(const float* __restrict__ Wq,
                                               const float* __restrict__ Wk,
                                               const float* __restrict__ Wv,
                                               _Float16* __restrict__ WtF) {
  const int w  = blockIdx.x >> 4;              // which W
  const int kt = blockIdx.x & 15;              // k-tile of 64
  const float* src = (w == 0) ? Wq : (w == 1 ? Wk : Wv);
  __shared__ _Float16 ls[64][72];              // [local k][n], padded
  const int t = threadIdx.x;
  {
    int rr = t >> 4;                           // 0..15
    int c4 = (t & 15) * 4;
    #pragma unroll
    for (int ri = 0; ri < 4; ++ri) {
      int k = rr + ri * 16;                    // local k 0..63
      f32x4 f = *(const f32x4*)&src[(size_t)(kt * 64 + k) * 64 + c4];
      #pragma unroll
      for (int j = 0; j < 4; ++j) ls[k][c4 + j] = (_Float16)f[j];
    }
  }
  __syncthreads();
  const int lane = t & 63, l16 = lane & 15, quad = lane >> 4;
  #pragma unroll
  for (int h = 0; h < 2; ++h) {
    int fid     = h * 4 + (t >> 6);            // 0..7
    int kstep_l = fid >> 2;                    // 0..1
    int ntl     = fid & 3;                     // 0..3
    int nt      = w * 4 + ntl;
    int kstep   = kt * 2 + kstep_l;
    f16x8 o;
    #pragma unroll
    for (int j = 0; j < 8; ++j) o[j] = ls[kstep_l * 32 + quad * 8 + j][ntl * 16 + l16];
    *(f16x8*)&WtF[((size_t)(kstep * 12 + nt) * 64 + lane) * 8] = o;
  }
}

// ---------------------------------------------------------------------------
// Kernel 2: QKV projection. ROUND 12: (a) epilogue bounces C through the
// dead xs LDS and emits 12 x 1KB fully-coalesced frag-order f16x8 bursts
// (was 12 scattered scalar f16 stores/thread -- the address-divergence class
// r11 proved expensive); (b) explicit static double-buffer on the 3 B-frags
// (load kstep+1 before kstep's MFMAs) so the L2 B-loads can't be sunk into
// per-kstep load-use serialization at the 128-VGPR cap.
// XCD-aligned block remap kept (batch = bid&7). Frag layouts (per batch b):
//   qfr[(b*128+qt)*2+h][lane][j] = Q[b][qt*16+(lane&15)][h*32+(lane>>4)*8+j]
//   kfr same; vfr[(b*64+ks)*4+dt][lane][j] = V[b][ks*32+(lane>>4)*8+j][dt*16+(lane&15)]
__global__ __launch_bounds__(512, 4) void qkv_gemm(const float* __restrict__ x,
                                                   const _Float16* __restrict__ WtF,
                                                   const float* __restrict__ bq,
                                                   const float* __restrict__ bk,
                                                   const float* __restrict__ bv,
                                                   _Float16* __restrict__ qfr,
                                                   _Float16* __restrict__ kfr,
                                                   _Float16* __restrict__ vfr) {
  __shared__ _Float16 xs[32 * 1024];           // exactly 64 KB
  const int tid  = threadIdx.x;
  const int wave = tid >> 6, lane = tid & 63;
  const int l16  = lane & 15, quad = lane >> 4;
  const int mhalf = wave >> 2;                 // 0..1
  const int ngrp  = wave & 3;                  // 0..3
  const int bid   = blockIdx.x;
  const int m0    = (((bid & 7) << 6) + (bid >> 3)) * 32;  // batch=bid&7, tile=bid>>3

  // --- stage x tile (fp32 -> f16), coalesced: 16-lane groups read 256B runs
  {
    int row   = tid >> 4;                      // 0..31
    int cbase = (tid & 15) * 4;
    const float* xrow = x + (size_t)(m0 + row) * 1024;
    int key = row & 7;
    #pragma unroll
    for (int j = 0; j < 16; ++j) {
      int col = cbase + j * 64;
      f32x4 f = *(const f32x4*)&xrow[col];
      f16x4 hh;
      #pragma unroll
      for (int e = 0; e < 4; ++e) hh[e] = (_Float16)f[e];
      int g   = col >> 3;                      // granule index 0..127
      int sub = col & 7;                       // 0 or 4
      *(f16x4*)&xs[(size_t)row * 1024 + (size_t)((g ^ key) << 3) + sub] = hh;
    }
  }
  __syncthreads();

  f32x4 acc0 = (f32x4){0.f,0.f,0.f,0.f};
  f32x4 acc1 = (f32x4){0.f,0.f,0.f,0.f};
  f32x4 acc2 = (f32x4){0.f,0.f,0.f,0.f};

  const int arow = mhalf * 16 + l16;
  const _Float16* abase = xs + (size_t)arow * 1024;
  const int akey = arow & 7;
  const _Float16* wbase = WtF + ((size_t)(ngrp * 3) * 64 + lane) * 8;

  // --- K-loop with explicit B double-buffer (b) ---
  f16x8 bc0 = *(const f16x8*)(wbase);
  f16x8 bc1 = *(const f16x8*)(wbase + 512);
  f16x8 bc2 = *(const f16x8*)(wbase + 1024);
  #pragma unroll 2
  for (int kstep = 0; kstep < 32; ++kstep) {
    const int kn = (kstep + 1) & 31;           // last iter reloads kstep 0 (unused)
    const _Float16* wkn = wbase + (size_t)kn * (12 * 64 * 8);
    f16x8 bn0 = *(const f16x8*)(wkn);
    f16x8 bn1 = *(const f16x8*)(wkn + 512);
    f16x8 bn2 = *(const f16x8*)(wkn + 1024);
    f16x8 a = *(const f16x8*)(abase + (((kstep * 4 + quad) ^ akey) << 3));
    acc0 = __builtin_amdgcn_mfma_f32_16x16x32_f16(a, bc0, acc0, 0, 0, 0);
    acc1 = __builtin_amdgcn_mfma_f32_16x16x32_f16(a, bc1, acc1, 0, 0, 0);
    acc2 = __builtin_amdgcn_mfma_f32_16x16x32_f16(a, bc2, acc2, 0, 0, 0);
    bc0 = bn0; bc1 = bn1; bc2 = bn2;
  }

  // --- epilogue (a): C -> LDS (bias folded), then 1KB frag-order bursts ---
  __syncthreads();                             // all A-frag ds_reads done
  _Float16 (*ls)[200] = (_Float16 (*)[200])xs; // 32 x 200 f16 = 12.8 KB
  {
    f32x4 accs[3] = {acc0, acc1, acc2};
    #pragma unroll
    for (int i = 0; i < 3; ++i) {
      int nt  = ngrp * 3 + i;
      int col = nt * 16 + l16;
      float bias = (nt < 4) ? bq[col] : (nt < 8) ? bk[col - 64] : bv[col - 128];
      #pragma unroll
      for (int r = 0; r < 4; ++r)
        ls[mhalf * 16 + quad * 4 + r][col] = (_Float16)(accs[i][r] + bias);
    }
  }
  __syncthreads();
  {
    const int batch = m0 >> 11;
    const int s0    = m0 & 2047;               // multiple of 32
    const int qt0   = s0 >> 4;
    // waves 0..7 -> Q frags (f<4: qtl=f>>1, h=f&1) / K frags (f-4)
    {
      const int f   = wave;
      const int qtl = (f >> 1) & 1, h = f & 1;
      const int cb  = (f >= 4 ? 64 : 0) + h * 32 + quad * 8;
      f16x8 v = *(const f16x8*)&ls[qtl * 16 + l16][cb];
      _Float16* dst = (f >= 4 ? kfr : qfr)
          + ((size_t)((batch * 128 + qt0 + qtl) * 2 + h)) * 512 + lane * 8;
      *(f16x8*)dst = v;
    }
    // waves 0..3 also emit the 4 V frags (transposed gather from ls)
    if (wave < 4) {
      const int dt = wave;
      f16x8 v;
      #pragma unroll
      for (int j = 0; j < 8; ++j) v[j] = ls[quad * 8 + j][128 + dt * 16 + l16];
      _Float16* dst = vfr
          + (((size_t)(batch * 64 + (s0 >> 5)) * 4 + dt)) * 512 + lane * 8;
      *(f16x8*)dst = v;
    }
  }
}

// ---------------------------------------------------------------------------
// Kernel 3: causal attention -- UNCHANGED from round 11 (looped per-wave
// flash, register double-buffer, frag-order 1KB-burst loads, online softmax,
// in-block 2-way LSE merge). Frozen for clean attribution of the qkv change.
__global__ __launch_bounds__(256, 2) void attn(const _Float16* __restrict__ qfr,
                                               const _Float16* __restrict__ kfr,
                                               const _Float16* __restrict__ vfr,
                                               float* __restrict__ out) {
  const int blk  = blockIdx.x;
  const int pair = blk >> 3;                   // 0..63
  const int b    = blk & 7;                    // batch == writer XCD slot
  const int tid  = threadIdx.x;
  const int w    = tid >> 6, lane = tid & 63;
  const int l16  = lane & 15, quad = lane >> 4;
  const int whichq = w >> 1;                   // 0: qtA, 1: qtB
  const int half   = w & 1;                    // kv-half within the q-tile
  const int qt   = whichq ? (127 - pair) : pair;
  const int q0   = qt * 16;
  const int qrow = q0 + l16;
  const int nt   = (qt >> 2) + 1;              // kv tiles of 64 (ceil((q0+16)/64))
  const int nh0  = (nt + 1) >> 1;
  const int t0   = half ? nh0 : 0;
  const int t1   = half ? nt : nh0;

  // per-wave P (f16[16][72], 2304B) overlaid with ob (f32[16][68], 4352B)
  __shared__ __align__(16) unsigned char sbuf[4][4352];
  __shared__ float mlb[4][2][16];
  _Float16 (*Pw)[72]  = (_Float16 (*)[72])&sbuf[w][0];
  float    (*obw)[68] = (float    (*)[68])&sbuf[w][0];

  // frag-order bases: every load is base + lane*8 (1KB wave-burst)
  const _Float16* qb = qfr + ((size_t)(b * 128 + qt) * 2) * 512 + lane * 8;
  const _Float16* kb = kfr + ((size_t)b * 128 * 2) * 512 + lane * 8;
  const _Float16* vb = vfr + ((size_t)b * 64 * 4) * 512 + lane * 8;

  const f16x8 qf0 = *(const f16x8*)(qb);
  const f16x8 qf1 = *(const f16x8*)(qb + 512);

  const float L2E = 1.44269504088896340736f;
  float m = -1e30f, l = 0.f;
  f32x4 o_[4];
  #pragma unroll
  for (int i = 0; i < 4; ++i) o_[i] = (f32x4){0.f, 0.f, 0.f, 0.f};

  // static double buffers (rule #20: no runtime indexing)
  f16x8 kfA[4][2], kfB[4][2], vfA[2][4], vfB[2][4];

  auto LOADT = [&](f16x8 (&kf)[4][2], f16x8 (&vf)[2][4], int t) {
    const _Float16* kp = kb + (size_t)t * 4096;
    #pragma unroll
    for (int st = 0; st < 4; ++st) {
      kf[st][0] = *(const f16x8*)(kp + st * 1024);
      kf[st][1] = *(const f16x8*)(kp + st * 1024 + 512);
    }
    const _Float16* vp = vb + (size_t)t * 4096;
    #pragma unroll
    for (int ks = 0; ks < 2; ++ks)
      #pragma unroll
      for (int dt = 0; dt < 4; ++dt)
        vf[ks][dt] = *(const f16x8*)(vp + ks * 2048 + dt * 512);
  };

  auto COMPUTE = [&](const f16x8 (&kf)[4][2], const f16x8 (&vf)[2][4], int t) {
    const int kvb = t * 64;
    f32x4 sc[4];
    #pragma unroll
    for (int st = 0; st < 4; ++st) {
      f32x4 cc = (f32x4){0.f, 0.f, 0.f, 0.f};
      cc = __builtin_amdgcn_mfma_f32_16x16x32_f16(kf[st][0], qf0, cc, 0, 0, 0);
      cc = __builtin_amdgcn_mfma_f32_16x16x32_f16(kf[st][1], qf1, cc, 0, 0, 0);
      sc[st] = cc;
    }
    if (kvb + 63 > q0) {                       // diagonal tile: causal mask
      #pragma unroll
      for (int st = 0; st < 4; ++st)
        #pragma unroll
        for (int r = 0; r < 4; ++r)
          if (kvb + st * 16 + quad * 4 + r > qrow) sc[st][r] = -1e30f;
    }
    float mx = -1e30f;
    #pragma unroll
    for (int st = 0; st < 4; ++st)
      mx = fmaxf(mx, fmaxf(fmaxf(sc[st][0], sc[st][1]), fmaxf(sc[st][2], sc[st][3])));
    mx = fmaxf(mx, __shfl_xor(mx, 16, 64));
    mx = fmaxf(mx, __shfl_xor(mx, 32, 64));
    const float mnew  = fmaxf(m, mx);
    const float alpha = exp2f((m - mnew) * L2E);
    m = mnew;
    float s = 0.f;
    #pragma unroll
    for (int st = 0; st < 4; ++st) {
      #pragma unroll
      for (int r = 0; r < 4; ++r) sc[st][r] = exp2f((sc[st][r] - m) * L2E);
      s += (sc[st][0] + sc[st][1]) + (sc[st][2] + sc[st][3]);
    }
    s += __shfl_xor(s, 16, 64);
    s += __shfl_xor(s, 32, 64);
    l = l * alpha + s;
    #pragma unroll
    for (int dt = 0; dt < 4; ++dt)
      #pragma unroll
      for (int r = 0; r < 4; ++r) o_[dt][r] *= alpha;
    #pragma unroll
    for (int st = 0; st < 4; ++st) {
      f16x4 ph;
      #pragma unroll
      for (int r = 0; r < 4; ++r) ph[r] = (_Float16)sc[st][r];
      *(f16x4*)&Pw[l16][st * 16 + quad * 4] = ph;
    }
    asm volatile("s_waitcnt lgkmcnt(0)" ::: "memory");
    __builtin_amdgcn_sched_barrier(0);
    #pragma unroll
    for (int ks = 0; ks < 2; ++ks) {
      f16x8 pf = *(const f16x8*)&Pw[l16][ks * 32 + quad * 8];
      #pragma unroll
      for (int dt = 0; dt < 4; ++dt)
        o_[dt] = __builtin_amdgcn_mfma_f32_16x16x32_f16(vf[ks][dt], pf, o_[dt], 0, 0, 0);
    }
  };

  // software-pipelined kv loop: load t+1 before computing t
  int t = t0;
  if (t < t1) {
    LOADT(kfA, vfA, t);
    while (t + 1 < t1) {
      LOADT(kfB, vfB, t + 1);
      __builtin_amdgcn_sched_barrier(0);
      COMPUTE(kfA, vfA, t);
      if (t + 2 < t1) {
        LOADT(kfA, vfA, t + 2);
        __builtin_amdgcn_sched_barrier(0);
      }
      COMPUTE(kfB, vfB, t + 1);
      t += 2;
    }
    if (t < t1) COMPUTE(kfA, vfA, t);
  }

  // publish per-wave partials: obw[q][d] = O[d][q]^T, (m,l) per q-row
  #pragma unroll
  for (int dt = 0; dt < 4; ++dt)
    *(f32x4*)&obw[l16][dt * 16 + quad * 4] = o_[dt];
  if (quad == 0) {
    mlb[w][0][l16] = m;
    mlb[w][1][l16] = l;
  }
  __syncthreads();

  // 2-way LSE merge per q-tile: waves (0,1) -> qtA, (2,3) -> qtB
  {
    const int grp = tid >> 7;                  // 0: qtA, 1: qtB
    const int idx = tid & 127;
    const int row = idx >> 3;
    const int c8  = (idx & 7) * 8;
    const int wb  = grp * 2;
    const int qtg = grp ? (127 - pair) : pair;
    const float m0v = mlb[wb][0][row], m1v = mlb[wb + 1][0][row];
    const float M   = fmaxf(m0v, m1v);
    const float w0  = exp2f((m0v - M) * L2E);
    const float w1  = exp2f((m1v - M) * L2E);
    const float L   = w0 * mlb[wb][1][row] + w1 * mlb[wb + 1][1][row];
    const float inv = 1.0f / (L * 32.0f);      // sqrt(H)=32 applied AFTER softmax
    const float (*oA)[68] = (const float (*)[68])&sbuf[wb][0];
    const float (*oB)[68] = (const float (*)[68])&sbuf[wb + 1][0];
    float* dst = out + ((size_t)b * 2048 + qtg * 16 + row) * 64 + c8;
    #pragma unroll
    for (int j = 0; j < 2; ++j) {
      f32x4 a = *(const f32x4*)&oA[row][c8 + j * 4];
      f32x4 bb = *(const f32x4*)&oB[row][c8 + j * 4];
      f32x4 r;
      #pragma unroll
      for (int e = 0; e < 4; ++e) r[e] = (w0 * a[e] + w1 * bb[e]) * inv;
      *(f32x4*)&dst[j * 4] = r;
    }
  }
}

// ---------------------------------------------------------------------------
extern "C" void kernel_launch(void* const* d_in, const int* in_sizes, int n_in,
                              void* d_out, int out_size, void* d_ws, size_t ws_size,
                              hipStream_t stream) {
  const float* x  = (const float*)d_in[0];
  const float* Wq = (const float*)d_in[1];
  const float* bq = (const float*)d_in[2];
  const float* Wk = (const float*)d_in[3];
  const float* bk = (const float*)d_in[4];
  const float* Wv = (const float*)d_in[5];
  const float* bv = (const float*)d_in[6];
  float* out = (float*)d_out;

  // ws layout (f16): WtF 192*1024 | qfr 1M | kfr 1M | vfr 1M  (~6.7MB)
  _Float16* WtF = (_Float16*)d_ws;
  _Float16* qfr = WtF + 192 * 1024;
  _Float16* kfr = qfr + (size_t)8 * 128 * 2 * 512;
  _Float16* vfr = kfr + (size_t)8 * 128 * 2 * 512;

  hipLaunchKernelGGL(wt_prep,  dim3(48),  dim3(256), 0, stream, Wq, Wk, Wv, WtF);
  hipLaunchKernelGGL(qkv_gemm, dim3(512), dim3(512), 0, stream, x, WtF, bq, bk, bv, qfr, kfr, vfr);
  hipLaunchKernelGGL(attn,     dim3(512), dim3(256), 0, stream, qfr, kfr, vfr, out);
}